// Round 1
// baseline (240.829 us; speedup 1.0000x reference)
//
#include <hip/hip_runtime.h>

// Problem constants (match reference)
#define S_LEN 4096
#define DMODEL 1024
#define NH 16
#define DH 64
#define WIN 256
#define NQKV 3072  // fused QKV output width

typedef __attribute__((ext_vector_type(8))) short short8;
typedef __attribute__((ext_vector_type(4))) short sh4;
typedef __attribute__((ext_vector_type(4))) float floatx4;

__device__ __forceinline__ ushort f2bf(float f) {
    union { float f; unsigned int i; } x;
    x.f = f;
    unsigned int r = x.i + 0x7FFFu + ((x.i >> 16) & 1u);  // RNE
    return (ushort)(r >> 16);
}

// ---------------------------------------------------------------------------
// Fused fp32 -> bf16 convert for x, wq, wk, wv, wo in ONE dispatch.
// ---------------------------------------------------------------------------
__global__ __launch_bounds__(256) void cvt_all(const float* __restrict__ x,
                                               const float* __restrict__ wq,
                                               const float* __restrict__ wk,
                                               const float* __restrict__ wv,
                                               const float* __restrict__ wo,
                                               ushort* __restrict__ xb,
                                               ushort* __restrict__ W3b,
                                               ushort* __restrict__ wob,
                                               int nx8, int nw8) {
    int i = blockIdx.x * 256 + threadIdx.x;
    const float* src;
    ushort* dst;
    if (i < nx8) {
        src = x + (size_t)i * 8;            dst = xb + (size_t)i * 8;
    } else {
        int j = i - nx8;
        int which = j / nw8, r = j - which * nw8;
        if (which >= 4) return;
        const float* w4[4] = {wq, wk, wv, wo};
        src = w4[which] + (size_t)r * 8;
        dst = (which == 3 ? wob : W3b + (size_t)which * nw8 * 8) + (size_t)r * 8;
    }
    floatx4 f0 = *(const floatx4*)src;
    floatx4 f1 = *(const floatx4*)(src + 4);
    short8 v;
#pragma unroll
    for (int e = 0; e < 4; ++e) v[e] = (short)f2bf(f0[e]);
#pragma unroll
    for (int e = 0; e < 4; ++e) v[4 + e] = (short)f2bf(f1[e]);
    *(short8*)dst = v;
}

// ---------------------------------------------------------------------------
// 2-phase counted-vmcnt GEMM (catalog T3/T4-lite + T1 + T2-equivalent):
//   - 128 x (NF*32) tile, BK=32, 3 LDS buffers, stage(t+2) while compute(t)
//   - step end: s_waitcnt vmcnt(CH) lgkmcnt(0) + raw s_barrier (never drain
//     vmcnt to 0 in the main loop -> loads span ~2 K-steps of compute).
//     lgkmcnt(0) before the barrier closes the WAR race on the recycled
//     buffer (all frag ds_reads drained before any wave may restage it).
//   - frag-read swizzle for 64B rows: slot = (kseg + (r&3) + ((r>>2)&3)) & 3
//     puts the 16 rows of a frag read on all 8 mod-128B slots -> exact 2-way
//     (free) ds_read_b128; staging source per row is a permutation of one
//     contiguous 64B segment (coalescing preserved).
//   - XCD swizzle: each XCD owns an 8-row M-band, traversed column-major
//     (W-panel stays L2-resident; 8 A-panels = 2MB fit beside it).
// NF=8 -> 128x256 (QKV proj), NF=4 -> 128x128 (output proj). K multiple of 96+.
// ---------------------------------------------------------------------------
template <int NF, bool OUTF32>
__global__ __launch_bounds__(256, 2) void gemm_2ph(const ushort* __restrict__ A,
                                                   const ushort* __restrict__ W,
                                                   void* __restrict__ Cout,
                                                   int M, int N, int K) {
    constexpr int BN = NF * 32;
    constexpr int WCH = BN / 64;   // W gload_lds per thread per step
    __shared__ __align__(16) ushort As[3][128 * 32];  // 3 x 8 KB
    __shared__ __align__(16) ushort Ws[3][BN * 32];   // 3 x (BN/128)*8 KB

    const int tid = threadIdx.x;
    const int w = tid >> 6, l = tid & 63;
    const int lm = l & 15, quad = l >> 4;

    // XCD-aware block swizzle (bijective when gridDim.y % 8 == 0).
    int bx, by;
    {
        const int nbx = gridDim.x, nby = gridDim.y;
        if ((nby & 7) == 0) {
            const int lin = blockIdx.y * nbx + blockIdx.x;
            const int rpb = nby >> 3;
            const int xcd = lin & 7, idx = lin >> 3;
            bx = idx / rpb;
            by = xcd * rpb + (idx - bx * rpb);
        } else {
            bx = blockIdx.x;
            by = blockIdx.y;
        }
    }
    const int bm0 = by * 128, bn0 = bx * BN;
    const int wm = (w >> 1) * 64, wn = (w & 1) * (BN / 2);

    // Staging: LDS chunk n (16B) -> row n>>2, slot n&3. Slot s of row r holds
    // logical k-seg (s - swz(r)) & 3, swz(r) = ((r&3)+((r>>2)&3)) & 3.
    const ushort* Ag = A + (size_t)bm0 * K;
    const ushort* Wg = W + (size_t)bn0 * K;
    int aoff[2];
#pragma unroll
    for (int p = 0; p < 2; ++p) {
        int n = p * 256 + tid, r = n >> 2, s = n & 3;
        int ks = (s - (((r & 3) + ((r >> 2) & 3)) & 3)) & 3;
        aoff[p] = r * K + ks * 8;
    }
    int woff[WCH];
#pragma unroll
    for (int p = 0; p < WCH; ++p) {
        int n = p * 256 + tid, r = n >> 2, s = n & 3;
        int ks = (s - (((r & 3) + ((r >> 2) & 3)) & 3)) & 3;
        woff[p] = r * K + ks * 8;
    }

    auto stage = [&](int bf, int k0) {
        ushort* ad = &As[bf][tid * 8];
        ushort* wd = &Ws[bf][tid * 8];
#pragma unroll
        for (int p = 0; p < 2; ++p)
            __builtin_amdgcn_global_load_lds(
                (const __attribute__((address_space(1))) void*)(Ag + aoff[p] + k0),
                (__attribute__((address_space(3))) void*)(ad + p * 2048), 16, 0, 0);
#pragma unroll
        for (int p = 0; p < WCH; ++p)
            __builtin_amdgcn_global_load_lds(
                (const __attribute__((address_space(1))) void*)(Wg + woff[p] + k0),
                (__attribute__((address_space(3))) void*)(wd + p * 2048), 16, 0, 0);
    };

    floatx4 acc[4][NF] = {};
    // Frag-read slot is a pure lane constant: row = 16*a + lm -> swz(row)=swz(lm).
    const int fs = ((quad + (lm & 3) + ((lm >> 2) & 3)) & 3) * 8;

    const int nt = K >> 5;  // assumes nt >= 3 (K = 1024 here)
    stage(0, 0);
    stage(1, 32);
    // Oldest 2+WCH loads (buffer 0) must land before first reads.
    if constexpr (NF == 8) asm volatile("s_waitcnt vmcnt(6)" ::: "memory");
    else                   asm volatile("s_waitcnt vmcnt(4)" ::: "memory");
    __builtin_amdgcn_s_barrier();

    int rb = 0, sb = 2;
    for (int t = 0; t < nt; ++t) {
        if (t + 2 < nt) stage(sb, (t + 2) << 5);
        const ushort* Ac = As[rb];
        const ushort* Wc = Ws[rb];
        short8 af[4], wf[NF];
#pragma unroll
        for (int mi = 0; mi < 4; ++mi)
            af[mi] = *(const short8*)&Ac[(wm + mi * 16 + lm) * 32 + fs];
#pragma unroll
        for (int ni = 0; ni < NF; ++ni)
            wf[ni] = *(const short8*)&Wc[(wn + ni * 16 + lm) * 32 + fs];
#pragma unroll
        for (int mi = 0; mi < 4; ++mi)
#pragma unroll
            for (int ni = 0; ni < NF; ++ni)
                acc[mi][ni] = __builtin_amdgcn_mfma_f32_16x16x32_bf16(
                    af[mi], wf[ni], acc[mi][ni], 0, 0, 0);
        // Counted drain: next tile's loads landed, ours for t+2 stay in flight.
        if (t + 2 < nt) {
            if constexpr (NF == 8)
                asm volatile("s_waitcnt vmcnt(6) lgkmcnt(0)" ::: "memory");
            else
                asm volatile("s_waitcnt vmcnt(4) lgkmcnt(0)" ::: "memory");
        } else {
            asm volatile("s_waitcnt vmcnt(0) lgkmcnt(0)" ::: "memory");
        }
        __builtin_amdgcn_s_barrier();
        rb = (rb == 2) ? 0 : rb + 1;
        sb = (sb == 2) ? 0 : sb + 1;
    }

#pragma unroll
    for (int mi = 0; mi < 4; ++mi)
#pragma unroll
        for (int ni = 0; ni < NF; ++ni)
#pragma unroll
            for (int r = 0; r < 4; ++r) {
                int row = bm0 + wm + mi * 16 + quad * 4 + r;
                int col = bn0 + wn + ni * 16 + lm;
                if constexpr (OUTF32)
                    ((float*)Cout)[(size_t)row * N + col] = acc[mi][ni][r];
                else
                    ((ushort*)Cout)[(size_t)row * N + col] = f2bf(acc[mi][ni][r]);
            }
}

// ---------------------------------------------------------------------------
// MFMA sliding-window attention over fused QKV layout [M][3072].
// R9: Ps double-buffered (second per-group fence deleted); softmax split into
// interior (no mask eval) vs boundary subtiles. Vt pi-permuted rows (R8).
// ---------------------------------------------------------------------------
#define KSP 72    // Ks row stride (shorts)
#define VTP 136   // Vt row stride (shorts)
#define PSP 40    // Ps row stride (shorts)

__global__ __launch_bounds__(256) void swattn_mfma(const ushort* __restrict__ QKV,
                                                   ushort* __restrict__ O) {
    __shared__ __align__(16) ushort Ks[128 * KSP];        // 18432 B  [key][d]
    __shared__ __align__(16) ushort Vt[64 * VTP];         // 17408 B  [pi(d)][key]
    __shared__ __align__(16) ushort Ps[2][4 * 64 * PSP];  // 40960 B  dbuf per-wave [q][key32]
    __shared__ __align__(16) float lW[256];               // 1024 B

    const int j = blockIdx.x, h = blockIdx.y, b = blockIdx.z;
    const int tid = threadIdx.x;
    const int w = tid >> 6, l = tid & 63;
    const int quad = l >> 4, lc = l & 15;

    const size_t base = (size_t)b * S_LEN * NQKV + (size_t)h * DH;
    const ushort* Qp = QKV + base;               // row stride NQKV
    const ushort* Kp = QKV + base + DMODEL;
    const ushort* Vp = QKV + base + 2 * DMODEL;

    short8 qf[4][2];
#pragma unroll
    for (int nq = 0; nq < 4; ++nq)
#pragma unroll
        for (int kk = 0; kk < 2; ++kk)
            qf[nq][kk] = *(const short8*)(Qp +
                (size_t)(j * 256 + w * 64 + nq * 16 + lc) * NQKV + kk * 32 + quad * 8);

    floatx4 o[4][4] = {};
    float lsum[4] = {0.f, 0.f, 0.f, 0.f};

    const float sscale = 0.18033688011112042f;  // log2(e)/sqrt(64)
    const float M0 = 2.0f;                      // fixed shift (exact: shift-invariance)
    const int qlo = w * 64, qhi = w * 64 + 63;

    for (int c = 0; c < 4; ++c) {
        const int kg0 = (j - 1) * 256 + c * 128;
        if (kg0 < 0) continue;
        __syncthreads();
#pragma unroll
        for (int i = 0; i < 4; ++i) {
            int cc = i * 256 + tid, key = cc >> 3, seg = cc & 7;
            *(short8*)&Ks[key * KSP + seg * 8] =
                *(const short8*)(Kp + (size_t)(kg0 + key) * NQKV + seg * 8);
            short8 vv = *(const short8*)(Vp + (size_t)(kg0 + key) * NQKV + seg * 8);
#pragma unroll
            for (int e = 0; e < 8; ++e)
                Vt[(e * 8 + seg) * VTP + key] = (ushort)vv[e];  // pi(seg*8+e)=e*8+seg
        }
        __syncthreads();

        const int krel0 = c * 128 - 256;
#pragma unroll
        for (int g = 0; g < 4; ++g) {
            const int k0 = krel0 + g * 32;
            if (k0 > qhi || k0 + 31 < qlo - 255) continue;
            ushort* Pw = &Ps[g & 1][w * 64 * PSP];

            // S^T = K·Q^T : D[key][q], with fully-masked-subtile skip
            floatx4 st[2][4];
            const floatx4 zero = {};
#pragma unroll
            for (int kt = 0; kt < 2; ++kt) {
                short8 kf0 = *(const short8*)&Ks[(g * 32 + kt * 16 + lc) * KSP + quad * 8];
                short8 kf1 = *(const short8*)&Ks[(g * 32 + kt * 16 + lc) * KSP + 32 + quad * 8];
#pragma unroll
                for (int nq = 0; nq < 4; ++nq) {
                    int kmin = k0 + kt * 16, qmin = qlo + nq * 16;
                    if (kmin > qmin + 15 || kmin + 270 < qmin) {  // fully masked
                        st[kt][nq] = zero;
                        continue;
                    }
                    st[kt][nq] = __builtin_amdgcn_mfma_f32_16x16x32_bf16(kf0, qf[nq][0], zero, 0, 0, 0);
                    st[kt][nq] = __builtin_amdgcn_mfma_f32_16x16x32_bf16(kf1, qf[nq][1], st[kt][nq], 0, 0, 0);
                }
            }
#pragma unroll
            for (int kt = 0; kt < 2; ++kt)
#pragma unroll
                for (int nq = 0; nq < 4; ++nq) {
                    sh4 pv;
                    int kmin = k0 + kt * 16, qmin = qlo + nq * 16;
                    if (kmin > qmin + 15 || kmin + 270 < qmin) {           // fully masked
                        pv[0] = pv[1] = pv[2] = pv[3] = 0;
                    } else if (kmin + 15 <= qmin && kmin + 240 >= qmin) {  // interior: no mask
#pragma unroll
                        for (int r = 0; r < 4; ++r) {
                            float p = exp2f(st[kt][nq][r] * sscale - M0);
                            lsum[nq] += p;
                            pv[r] = (short)f2bf(p);
                        }
                    } else {                                               // boundary
#pragma unroll
                        for (int r = 0; r < 4; ++r) {
                            int krel = kmin + quad * 4 + r;  // C row = key
                            int qrel = qmin + lc;            // C col = q
                            bool valid = (krel <= qrel) && (krel + 255 >= qrel);
                            float p = valid ? exp2f(st[kt][nq][r] * sscale - M0) : 0.f;
                            lsum[nq] += p;
                            pv[r] = (short)f2bf(p);
                        }
                    }
                    *(sh4*)&Pw[(nq * 16 + lc) * PSP + kt * 16 + quad * 4] = pv;
                }
            __threadfence_block();  // P writes visible before lane-crossed reads

            // O += P·V : A=P[q][key] from Ps, B=V^T[d][key] from Vt (pi rows)
            short8 vf[4];
#pragma unroll
            for (int nd = 0; nd < 4; ++nd) {
                int prow = (lc & 7) * 8 + nd * 2 + (lc >> 3);  // pi(nd*16+lc)
                vf[nd] = *(const short8*)&Vt[prow * VTP + g * 32 + quad * 8];
            }
#pragma unroll
            for (int mq = 0; mq < 4; ++mq) {
                int qmin = qlo + mq * 16;
                if (k0 > qmin + 15 || k0 + 286 < qmin) continue;  // group fully masked
                short8 pf = *(const short8*)&Pw[(mq * 16 + lc) * PSP + quad * 8];
#pragma unroll
                for (int nd = 0; nd < 4; ++nd)
                    o[mq][nd] = __builtin_amdgcn_mfma_f32_16x16x32_bf16(pf, vf[nd], o[mq][nd], 0, 0, 0);
            }
            // no trailing fence: next group writes the OTHER Ps buffer; the
            // group-after-next is separated by the next group's fence.
        }
    }

#pragma unroll
    for (int nq = 0; nq < 4; ++nq) {
        lsum[nq] += __shfl_xor(lsum[nq], 16);
        lsum[nq] += __shfl_xor(lsum[nq], 32);
    }
    if (l < 16) {
#pragma unroll
        for (int nq = 0; nq < 4; ++nq) lW[w * 64 + nq * 16 + l] = lsum[nq];
    }
    __threadfence_block();
#pragma unroll
    for (int mq = 0; mq < 4; ++mq) {
        floatx4 lv = *(const floatx4*)&lW[w * 64 + mq * 16 + quad * 4];
#pragma unroll
        for (int r = 0; r < 4; ++r) {
            float inv = 1.f / lv[r];
            int token = j * 256 + w * 64 + mq * 16 + quad * 4 + r;
#pragma unroll
            for (int nd = 0; nd < 4; ++nd)
                O[(size_t)b * S_LEN * DMODEL + (size_t)token * DMODEL + h * DH + nd * 16 + lc] =
                    f2bf(o[mq][nd][r] * inv);
        }
    }
}

// ---------------------------------------------------------------------------
extern "C" void kernel_launch(void* const* d_in, const int* in_sizes, int n_in,
                              void* d_out, int out_size, void* d_ws, size_t ws_size,
                              hipStream_t stream) {
    const float* x  = (const float*)d_in[0];
    const float* wq = (const float*)d_in[1];
    const float* wk = (const float*)d_in[2];
    const float* wv = (const float*)d_in[3];
    const float* wo = (const float*)d_in[4];
    float* out = (float*)d_out;

    const int D = DMODEL;
    const int M = in_sizes[0] / D;  // B*S = 8192
    const int Bb = M / S_LEN;       // 2

    ushort* xb   = (ushort*)d_ws;
    ushort* W3b  = xb + (size_t)M * D;
    ushort* wob  = W3b + (size_t)NQKV * D;
    ushort* QKVb = wob + (size_t)D * D;
    ushort* Ob   = xb;  // overlay: xb dead after QKV GEMM

    const int nx8 = M * D / 8, nw8 = D * D / 8;
    const int ntot = nx8 + 4 * nw8;
    cvt_all<<<dim3((ntot + 255) / 256), dim3(256), 0, stream>>>(
        x, wq, wk, wv, wo, xb, W3b, wob, nx8, nw8);

    // Fused QKV projection: [M,3072] = xb @ W3b^T  (counted-vmcnt 2-phase)
    gemm_2ph<8, false><<<dim3(NQKV / 256, M / 128), dim3(256), 0, stream>>>(
        xb, W3b, QKVb, M, NQKV, D);

    swattn_mfma<<<dim3(S_LEN / WIN, NH, Bb), dim3(256), 0, stream>>>(QKVb, Ob);

    // Output projection: out[M,1024] = Ob @ wob^T (fp32 out)
    gemm_2ph<4, true><<<dim3(D / 128, M / 128), dim3(256), 0, stream>>>(
        Ob, wob, out, M, D, D);
}

// Round 2
// 232.044 us; speedup vs baseline: 1.0379x; 1.0379x over previous
//
#include <hip/hip_runtime.h>

// Problem constants (match reference)
#define S_LEN 4096
#define DMODEL 1024
#define NH 16
#define DH 64
#define WIN 256
#define NQKV 3072  // fused QKV output width

typedef __attribute__((ext_vector_type(8))) short short8;
typedef __attribute__((ext_vector_type(4))) short sh4;
typedef __attribute__((ext_vector_type(4))) float floatx4;

__device__ __forceinline__ ushort f2bf(float f) {
    union { float f; unsigned int i; } x;
    x.f = f;
    unsigned int r = x.i + 0x7FFFu + ((x.i >> 16) & 1u);  // RNE
    return (ushort)(r >> 16);
}

// ---------------------------------------------------------------------------
// Fused fp32 -> bf16 convert for x, wq, wk, wv, wo in ONE dispatch.
// ---------------------------------------------------------------------------
__global__ __launch_bounds__(256) void cvt_all(const float* __restrict__ x,
                                               const float* __restrict__ wq,
                                               const float* __restrict__ wk,
                                               const float* __restrict__ wv,
                                               const float* __restrict__ wo,
                                               ushort* __restrict__ xb,
                                               ushort* __restrict__ W3b,
                                               ushort* __restrict__ wob,
                                               int nx8, int nw8) {
    int i = blockIdx.x * 256 + threadIdx.x;
    const float* src;
    ushort* dst;
    if (i < nx8) {
        src = x + (size_t)i * 8;            dst = xb + (size_t)i * 8;
    } else {
        int j = i - nx8;
        int which = j / nw8, r = j - which * nw8;
        if (which >= 4) return;
        const float* w4[4] = {wq, wk, wv, wo};
        src = w4[which] + (size_t)r * 8;
        dst = (which == 3 ? wob : W3b + (size_t)which * nw8 * 8) + (size_t)r * 8;
    }
    floatx4 f0 = *(const floatx4*)src;
    floatx4 f1 = *(const floatx4*)(src + 4);
    short8 v;
#pragma unroll
    for (int e = 0; e < 4; ++e) v[e] = (short)f2bf(f0[e]);
#pragma unroll
    for (int e = 0; e < 4; ++e) v[4 + e] = (short)f2bf(f1[e]);
    *(short8*)dst = v;
}

// ---------------------------------------------------------------------------
// Sync / wait primitives for the pipelined GEMMs.
// ---------------------------------------------------------------------------
#define GLOAD16(src, dst)                                                     \
    __builtin_amdgcn_global_load_lds(                                         \
        (const __attribute__((address_space(1))) void*)(src),                 \
        (__attribute__((address_space(3))) void*)(dst), 16, 0, 0)
#define WAITV4 asm volatile("s_waitcnt vmcnt(4)" ::: "memory")
#define WAITV2 asm volatile("s_waitcnt vmcnt(2)" ::: "memory")
#define WAITV0 asm volatile("s_waitcnt vmcnt(0)" ::: "memory")
#define BARR   asm volatile("s_barrier" ::: "memory")
#define WAITL                                                                 \
    do {                                                                      \
        asm volatile("s_waitcnt lgkmcnt(0)" ::: "memory");                    \
        __builtin_amdgcn_sched_barrier(0);                                    \
    } while (0)

// ---------------------------------------------------------------------------
// 256x256 8-wave 4-phase counted-vmcnt GEMM (T3+T4+T5, zero-conflict XOR).
//   BK=64, 512 threads (2M x 4N waves), per-wave C = 128x64 (acc[8][4]).
//   LDS: 2 buffers x {A,B} x 2 quarter-units (16 KB each) = 128 KiB.
//   Units are striped to match read-need order:
//     A-unit u = rows r with (r>>6)&1==u  (riu = (r>>7)*64 + (r&63))
//     B-unit u = rows n with (n>>5)&1==u  (riu = (n>>6)*32 + (n&31))
//   Swizzle (proven 0-conflict at BK=64): chunk slot s holds k-seg s^(riu&7);
//   frag reads use slot=((kk*4+quad)^(l&7)) — riu&7 == l&7 for all reads.
//   Ledger (2 loads/thread/unit, issue order AQ1,BQ1,BQ2,AQ2 at P1..P4):
//     P1: vmcnt(4)  [BQ2(t) landed for P2]
//     P2: vmcnt(4)  [AQ2(t) landed for P3]
//     P3: none
//     P4: vmcnt(4)  [AQ1,BQ1(t+1) landed for next P1]  — never 0 mid-loop.
//   Epilogue tile: exact drains vmcnt(2)/vmcnt(0).
//   WAR safe: every phase's ds_reads drain at its lgkmcnt(0) (before MFMA,
//   before phase-end barrier); stages for the other buffer issue only after
//   that barrier.
// ---------------------------------------------------------------------------
template <bool OUTF32>
__global__ __launch_bounds__(512, 2) void gemm256(const ushort* __restrict__ A,
                                                  const ushort* __restrict__ W,
                                                  void* __restrict__ Cout,
                                                  int M, int N, int K) {
    __shared__ __align__(16) ushort AS[2][2][128 * 64];  // 64 KiB
    __shared__ __align__(16) ushort BS[2][2][128 * 64];  // 64 KiB

    const int tid = threadIdx.x;
    const int w = tid >> 6, l = tid & 63;
    const int lm = l & 15, quad = l >> 4, l7 = l & 7;
    const int mh = w >> 2;   // wave M-half (0/1)
    const int wq = w & 3;    // wave N-quarter (0..3)

    // XCD-aware block swizzle (bijective; gridDim.y % 8 == 0 here).
    int bx, by;
    {
        const int nbx = gridDim.x, nby = gridDim.y;
        if ((nby & 7) == 0) {
            const int lin = blockIdx.y * nbx + blockIdx.x;
            const int rpb = nby >> 3;
            const int xcd = lin & 7, idx = lin >> 3;
            bx = idx / rpb;
            by = xcd * rpb + (idx - bx * rpb);
        } else {
            bx = blockIdx.x;
            by = blockIdx.y;
        }
    }
    const int bm0 = by * 256, bn0 = bx * 256;

    const ushort* Ag = A + (size_t)bm0 * K;
    const ushort* Wg = W + (size_t)bn0 * K;

    // Per-thread staging addresses: chunk c = p*512+tid (16 B each),
    // riu = c>>3 (row-in-unit), k-seg = (c&7)^(riu&7)  [inverse of read swz].
    int ksOff[2], aRowB[2], bRowB[2];
#pragma unroll
    for (int p = 0; p < 2; ++p) {
        int c = p * 512 + tid, riu = c >> 3;
        ksOff[p] = ((c & 7) ^ (riu & 7)) * 8;
        aRowB[p] = (riu >> 6) * 128 + (riu & 63);  // + u*64 at issue
        bRowB[p] = (riu >> 5) * 64 + (riu & 31);   // + u*32 at issue
    }

    auto stA = [&](int bf, int u, int k0) {
#pragma unroll
        for (int p = 0; p < 2; ++p)
            GLOAD16(Ag + (size_t)(aRowB[p] + u * 64) * K + k0 + ksOff[p],
                    &AS[bf][u][(p * 512 + tid) * 8]);
    };
    auto stB = [&](int bf, int u, int k0) {
#pragma unroll
        for (int p = 0; p < 2; ++p)
            GLOAD16(Wg + (size_t)(bRowB[p] + u * 32) * K + k0 + ksOff[p],
                    &BS[bf][u][(p * 512 + tid) * 8]);
    };

    const int s0 = (quad ^ l7) * 8;        // slot for kk=0
    const int s1 = ((4 + quad) ^ l7) * 8;  // slot for kk=1

    floatx4 acc[8][4] = {};
    short8 aR[4][2], b0[2][2], b1[2][2];

    auto rdA = [&](int bf, int g, short8(&r)[4][2]) {
#pragma unroll
        for (int m = 0; m < 4; ++m) {
            const ushort* p = &AS[bf][g][(mh * 64 + m * 16 + lm) * 64];
            r[m][0] = *(const short8*)(p + s0);
            r[m][1] = *(const short8*)(p + s1);
        }
    };
    auto rdB = [&](int bf, int g, short8(&r)[2][2]) {
#pragma unroll
        for (int n = 0; n < 2; ++n) {
            const ushort* p = &BS[bf][g][(wq * 32 + n * 16 + lm) * 64];
            r[n][0] = *(const short8*)(p + s0);
            r[n][1] = *(const short8*)(p + s1);
        }
    };

#define MMAQ(AF, BF_, GM, GN)                                                  \
    do {                                                                       \
        __builtin_amdgcn_s_setprio(1);                                         \
        _Pragma("unroll") for (int m_ = 0; m_ < 4; ++m_)                       \
            _Pragma("unroll") for (int n_ = 0; n_ < 2; ++n_) {                 \
            acc[(GM)*4 + m_][(GN)*2 + n_] =                                    \
                __builtin_amdgcn_mfma_f32_16x16x32_bf16(                       \
                    AF[m_][0], BF_[n_][0], acc[(GM)*4 + m_][(GN)*2 + n_], 0,   \
                    0, 0);                                                     \
            acc[(GM)*4 + m_][(GN)*2 + n_] =                                    \
                __builtin_amdgcn_mfma_f32_16x16x32_bf16(                       \
                    AF[m_][1], BF_[n_][1], acc[(GM)*4 + m_][(GN)*2 + n_], 0,   \
                    0, 0);                                                     \
        }                                                                      \
        __builtin_amdgcn_s_setprio(0);                                         \
    } while (0)

    // Prologue: stage tile 0 in need-order; first two units must be landed.
    stA(0, 0, 0);
    stB(0, 0, 0);
    stB(0, 1, 0);
    stA(0, 1, 0);
    WAITV4;
    BARR;

    const int nt = K >> 6;  // 16
    for (int t = 0; t < nt; ++t) {
        const int bf = t & 1, nb = bf ^ 1, kn = (t + 1) << 6;
        const bool nl = (t + 1 < nt);
        // ---- P1: quad (M0 x N0); read A-g0 + B-g0; stage AQ1(t+1)
        rdA(bf, 0, aR);
        rdB(bf, 0, b0);
        if (nl) { stA(nb, 0, kn); WAITV4; } else { WAITV2; }
        BARR;
        WAITL;
        MMAQ(aR, b0, 0, 0);
        BARR;
        // ---- P2: quad (M0 x N1); read B-g1; stage BQ1(t+1)
        rdB(bf, 1, b1);
        if (nl) { stB(nb, 0, kn); WAITV4; } else { WAITV0; }
        BARR;
        WAITL;
        MMAQ(aR, b1, 0, 1);
        BARR;
        // ---- P3: quad (M1 x N1); read A-g1; stage BQ2(t+1); no vm wait
        rdA(bf, 1, aR);
        if (nl) stB(nb, 1, kn);
        BARR;
        WAITL;
        MMAQ(aR, b1, 1, 1);
        BARR;
        // ---- P4: quad (M1 x N0); no reads; stage AQ2(t+1)
        if (nl) { stA(nb, 1, kn); WAITV4; }
        BARR;
        MMAQ(aR, b0, 1, 0);
        BARR;
    }

#pragma unroll
    for (int mi = 0; mi < 8; ++mi)
#pragma unroll
        for (int ni = 0; ni < 4; ++ni)
#pragma unroll
            for (int r = 0; r < 4; ++r) {
                int row = bm0 + mh * 128 + mi * 16 + quad * 4 + r;
                int col = bn0 + wq * 64 + ni * 16 + lm;
                if constexpr (OUTF32)
                    ((float*)Cout)[(size_t)row * N + col] = acc[mi][ni][r];
                else
                    ((ushort*)Cout)[(size_t)row * N + col] = f2bf(acc[mi][ni][r]);
            }
#undef MMAQ
}

// ---------------------------------------------------------------------------
// R0-proven 128x256 BK=64 single-buffer GEMM (zero bank conflicts) + XCD
// swizzle — used for the output projection (grid 256 = 1 block/CU).
// ---------------------------------------------------------------------------
template <bool OUTF32>
__global__ __launch_bounds__(256, 2) void gemm128(const ushort* __restrict__ A,
                                                  const ushort* __restrict__ W,
                                                  void* __restrict__ Cout,
                                                  int M, int N, int K) {
    __shared__ __align__(16) ushort As[128 * 64];  // 16 KB
    __shared__ __align__(16) ushort Ws[256 * 64];  // 32 KB

    const int tid = threadIdx.x;
    const int w = tid >> 6, l = tid & 63;

    int bx, by;
    {
        const int nbx = gridDim.x, nby = gridDim.y;
        if ((nby & 7) == 0) {
            const int lin = blockIdx.y * nbx + blockIdx.x;
            const int rpb = nby >> 3;
            const int xcd = lin & 7, idx = lin >> 3;
            bx = idx / rpb;
            by = xcd * rpb + (idx - bx * rpb);
        } else {
            bx = blockIdx.x;
            by = blockIdx.y;
        }
    }
    const int bm0 = by * 128, bn0 = bx * 256;
    const int wm = (w >> 1) * 64, wn = (w & 1) * 128;
    const int lm = l & 15, quad = l >> 4;

    floatx4 acc[4][8] = {};

    // Staging: chunk c (16 B): row = c>>3, pos = c&7, global seg = pos^(row&7).
    int arow[4], acol[4];
#pragma unroll
    for (int p = 0; p < 4; ++p) {
        int c = p * 256 + tid;
        arow[p] = c >> 3;
        acol[p] = (((c & 7) ^ (arow[p] & 7))) * 8;
    }
    int wrow[8], wcol[8];
#pragma unroll
    for (int p = 0; p < 8; ++p) {
        int c = p * 256 + tid;
        wrow[p] = c >> 3;
        wcol[p] = (((c & 7) ^ (wrow[p] & 7))) * 8;
    }

    for (int k0 = 0; k0 < K; k0 += 64) {
#pragma unroll
        for (int p = 0; p < 4; ++p)
            GLOAD16(A + (size_t)(bm0 + arow[p]) * K + k0 + acol[p],
                    As + p * 2048 + tid * 8);
#pragma unroll
        for (int p = 0; p < 8; ++p)
            GLOAD16(W + (size_t)(bn0 + wrow[p]) * K + k0 + wcol[p],
                    Ws + p * 2048 + tid * 8);
        __syncthreads();  // drains vmcnt(0): staging complete

#pragma unroll
        for (int kk = 0; kk < 2; ++kk) {
            const int sseg = ((kk * 4 + quad) ^ (lm & 7)) * 8;
            short8 af[4], wf[8];
#pragma unroll
            for (int mi = 0; mi < 4; ++mi)
                af[mi] = *(const short8*)&As[(wm + mi * 16 + lm) * 64 + sseg];
#pragma unroll
            for (int ni = 0; ni < 8; ++ni)
                wf[ni] = *(const short8*)&Ws[(wn + ni * 16 + lm) * 64 + sseg];
#pragma unroll
            for (int mi = 0; mi < 4; ++mi)
#pragma unroll
                for (int ni = 0; ni < 8; ++ni)
                    acc[mi][ni] = __builtin_amdgcn_mfma_f32_16x16x32_bf16(
                        af[mi], wf[ni], acc[mi][ni], 0, 0, 0);
        }
        __syncthreads();  // frag reads done before next staging overwrites
    }

#pragma unroll
    for (int mi = 0; mi < 4; ++mi)
#pragma unroll
        for (int ni = 0; ni < 8; ++ni)
#pragma unroll
            for (int r = 0; r < 4; ++r) {
                int row = bm0 + wm + mi * 16 + quad * 4 + r;
                int col = bn0 + wn + ni * 16 + lm;
                if constexpr (OUTF32)
                    ((float*)Cout)[(size_t)row * N + col] = acc[mi][ni][r];
                else
                    ((ushort*)Cout)[(size_t)row * N + col] = f2bf(acc[mi][ni][r]);
            }
}

// ---------------------------------------------------------------------------
// MFMA sliding-window attention over fused QKV layout [M][3072]. (unchanged)
// ---------------------------------------------------------------------------
#define KSP 72    // Ks row stride (shorts)
#define VTP 136   // Vt row stride (shorts)
#define PSP 40    // Ps row stride (shorts)

__global__ __launch_bounds__(256) void swattn_mfma(const ushort* __restrict__ QKV,
                                                   ushort* __restrict__ O) {
    __shared__ __align__(16) ushort Ks[128 * KSP];        // 18432 B  [key][d]
    __shared__ __align__(16) ushort Vt[64 * VTP];         // 17408 B  [pi(d)][key]
    __shared__ __align__(16) ushort Ps[2][4 * 64 * PSP];  // 40960 B  dbuf per-wave [q][key32]
    __shared__ __align__(16) float lW[256];               // 1024 B

    const int j = blockIdx.x, h = blockIdx.y, b = blockIdx.z;
    const int tid = threadIdx.x;
    const int w = tid >> 6, l = tid & 63;
    const int quad = l >> 4, lc = l & 15;

    const size_t base = (size_t)b * S_LEN * NQKV + (size_t)h * DH;
    const ushort* Qp = QKV + base;               // row stride NQKV
    const ushort* Kp = QKV + base + DMODEL;
    const ushort* Vp = QKV + base + 2 * DMODEL;

    short8 qf[4][2];
#pragma unroll
    for (int nq = 0; nq < 4; ++nq)
#pragma unroll
        for (int kk = 0; kk < 2; ++kk)
            qf[nq][kk] = *(const short8*)(Qp +
                (size_t)(j * 256 + w * 64 + nq * 16 + lc) * NQKV + kk * 32 + quad * 8);

    floatx4 o[4][4] = {};
    float lsum[4] = {0.f, 0.f, 0.f, 0.f};

    const float sscale = 0.18033688011112042f;  // log2(e)/sqrt(64)
    const float M0 = 2.0f;                      // fixed shift (exact: shift-invariance)
    const int qlo = w * 64, qhi = w * 64 + 63;

    for (int c = 0; c < 4; ++c) {
        const int kg0 = (j - 1) * 256 + c * 128;
        if (kg0 < 0) continue;
        __syncthreads();
#pragma unroll
        for (int i = 0; i < 4; ++i) {
            int cc = i * 256 + tid, key = cc >> 3, seg = cc & 7;
            *(short8*)&Ks[key * KSP + seg * 8] =
                *(const short8*)(Kp + (size_t)(kg0 + key) * NQKV + seg * 8);
            short8 vv = *(const short8*)(Vp + (size_t)(kg0 + key) * NQKV + seg * 8);
#pragma unroll
            for (int e = 0; e < 8; ++e)
                Vt[(e * 8 + seg) * VTP + key] = (ushort)vv[e];  // pi(seg*8+e)=e*8+seg
        }
        __syncthreads();

        const int krel0 = c * 128 - 256;
#pragma unroll
        for (int g = 0; g < 4; ++g) {
            const int k0 = krel0 + g * 32;
            if (k0 > qhi || k0 + 31 < qlo - 255) continue;
            ushort* Pw = &Ps[g & 1][w * 64 * PSP];

            // S^T = K·Q^T : D[key][q], with fully-masked-subtile skip
            floatx4 st[2][4];
            const floatx4 zero = {};
#pragma unroll
            for (int kt = 0; kt < 2; ++kt) {
                short8 kf0 = *(const short8*)&Ks[(g * 32 + kt * 16 + lc) * KSP + quad * 8];
                short8 kf1 = *(const short8*)&Ks[(g * 32 + kt * 16 + lc) * KSP + 32 + quad * 8];
#pragma unroll
                for (int nq = 0; nq < 4; ++nq) {
                    int kmin = k0 + kt * 16, qmin = qlo + nq * 16;
                    if (kmin > qmin + 15 || kmin + 270 < qmin) {  // fully masked
                        st[kt][nq] = zero;
                        continue;
                    }
                    st[kt][nq] = __builtin_amdgcn_mfma_f32_16x16x32_bf16(kf0, qf[nq][0], zero, 0, 0, 0);
                    st[kt][nq] = __builtin_amdgcn_mfma_f32_16x16x32_bf16(kf1, qf[nq][1], st[kt][nq], 0, 0, 0);
                }
            }
#pragma unroll
            for (int kt = 0; kt < 2; ++kt)
#pragma unroll
                for (int nq = 0; nq < 4; ++nq) {
                    sh4 pv;
                    int kmin = k0 + kt * 16, qmin = qlo + nq * 16;
                    if (kmin > qmin + 15 || kmin + 270 < qmin) {           // fully masked
                        pv[0] = pv[1] = pv[2] = pv[3] = 0;
                    } else if (kmin + 15 <= qmin && kmin + 240 >= qmin) {  // interior: no mask
#pragma unroll
                        for (int r = 0; r < 4; ++r) {
                            float p = exp2f(st[kt][nq][r] * sscale - M0);
                            lsum[nq] += p;
                            pv[r] = (short)f2bf(p);
                        }
                    } else {                                               // boundary
#pragma unroll
                        for (int r = 0; r < 4; ++r) {
                            int krel = kmin + quad * 4 + r;  // C row = key
                            int qrel = qmin + lc;            // C col = q
                            bool valid = (krel <= qrel) && (krel + 255 >= qrel);
                            float p = valid ? exp2f(st[kt][nq][r] * sscale - M0) : 0.f;
                            lsum[nq] += p;
                            pv[r] = (short)f2bf(p);
                        }
                    }
                    *(sh4*)&Pw[(nq * 16 + lc) * PSP + kt * 16 + quad * 4] = pv;
                }
            __threadfence_block();  // P writes visible before lane-crossed reads

            // O += P·V : A=P[q][key] from Ps, B=V^T[d][key] from Vt (pi rows)
            short8 vf[4];
#pragma unroll
            for (int nd = 0; nd < 4; ++nd) {
                int prow = (lc & 7) * 8 + nd * 2 + (lc >> 3);  // pi(nd*16+lc)
                vf[nd] = *(const short8*)&Vt[prow * VTP + g * 32 + quad * 8];
            }
#pragma unroll
            for (int mq = 0; mq < 4; ++mq) {
                int qmin = qlo + mq * 16;
                if (k0 > qmin + 15 || k0 + 286 < qmin) continue;  // group fully masked
                short8 pf = *(const short8*)&Pw[(mq * 16 + lc) * PSP + quad * 8];
#pragma unroll
                for (int nd = 0; nd < 4; ++nd)
                    o[mq][nd] = __builtin_amdgcn_mfma_f32_16x16x32_bf16(pf, vf[nd], o[mq][nd], 0, 0, 0);
            }
            // no trailing fence: next group writes the OTHER Ps buffer; the
            // group-after-next is separated by the next group's fence.
        }
    }

#pragma unroll
    for (int nq = 0; nq < 4; ++nq) {
        lsum[nq] += __shfl_xor(lsum[nq], 16);
        lsum[nq] += __shfl_xor(lsum[nq], 32);
    }
    if (l < 16) {
#pragma unroll
        for (int nq = 0; nq < 4; ++nq) lW[w * 64 + nq * 16 + l] = lsum[nq];
    }
    __threadfence_block();
#pragma unroll
    for (int mq = 0; mq < 4; ++mq) {
        floatx4 lv = *(const floatx4*)&lW[w * 64 + mq * 16 + quad * 4];
#pragma unroll
        for (int r = 0; r < 4; ++r) {
            float inv = 1.f / lv[r];
            int token = j * 256 + w * 64 + mq * 16 + quad * 4 + r;
#pragma unroll
            for (int nd = 0; nd < 4; ++nd)
                O[(size_t)b * S_LEN * DMODEL + (size_t)token * DMODEL + h * DH + nd * 16 + lc] =
                    f2bf(o[mq][nd][r] * inv);
        }
    }
}

// ---------------------------------------------------------------------------
extern "C" void kernel_launch(void* const* d_in, const int* in_sizes, int n_in,
                              void* d_out, int out_size, void* d_ws, size_t ws_size,
                              hipStream_t stream) {
    const float* x  = (const float*)d_in[0];
    const float* wq = (const float*)d_in[1];
    const float* wk = (const float*)d_in[2];
    const float* wv = (const float*)d_in[3];
    const float* wo = (const float*)d_in[4];
    float* out = (float*)d_out;

    const int D = DMODEL;
    const int M = in_sizes[0] / D;  // B*S = 8192
    const int Bb = M / S_LEN;       // 2

    ushort* xb   = (ushort*)d_ws;
    ushort* W3b  = xb + (size_t)M * D;
    ushort* wob  = W3b + (size_t)NQKV * D;
    ushort* QKVb = wob + (size_t)D * D;
    ushort* Ob   = xb;  // overlay: xb dead after QKV GEMM

    const int nx8 = M * D / 8, nw8 = D * D / 8;
    const int ntot = nx8 + 4 * nw8;
    cvt_all<<<dim3((ntot + 255) / 256), dim3(256), 0, stream>>>(
        x, wq, wk, wv, wo, xb, W3b, wob, nx8, nw8);

    // Fused QKV projection: [M,3072] = xb @ W3b^T  (256² 4-phase pipeline)
    gemm256<false><<<dim3(NQKV / 256, M / 256), dim3(512), 0, stream>>>(
        xb, W3b, QKVb, M, NQKV, D);

    swattn_mfma<<<dim3(S_LEN / WIN, NH, Bb), dim3(256), 0, stream>>>(QKVb, Ob);

    // Output projection: out[M,1024] = Ob @ wob^T (fp32 out, proven structure)
    gemm128<true><<<dim3(D / 256, M / 128), dim3(256), 0, stream>>>(
        Ob, wob, out, M, D, D);
}